// Round 1
// baseline (117.589 us; speedup 1.0000x reference)
//
#include <hip/hip_runtime.h>
#include <math.h>

// Problem constants (from reference): VOCAB=2048, CHORD_VOCAB=60, WINDOW=8
// total = main_ce + 0.05*rep + 0.2*chord_ce + 0.1*scale_bce
// rep_loss is data-independent: 0.5 * sum_pos min(pos,8) / (S*VOCAB)
// (one-hot rows sum to 1 since ids are always in [0,VOCAB)).

#define VOCAB 2048
#define CHORDV 60

__device__ __forceinline__ float waveRedMax(float v) {
#pragma unroll
    for (int off = 32; off > 0; off >>= 1)
        v = fmaxf(v, __shfl_xor(v, off, 64));
    return v;
}

__device__ __forceinline__ float waveRedSum(float v) {
#pragma unroll
    for (int off = 32; off > 0; off >>= 1)
        v += __shfl_xor(v, off, 64);
    return v;
}

// ---------------- main CE: one block (256 thr) per row of 2048 ----------------
__global__ __launch_bounds__(256) void ce_main_kernel(
    const float* __restrict__ logits, const int* __restrict__ tgt,
    float* __restrict__ nll_out, float* __restrict__ valid_out) {
    const int row = blockIdx.x;
    const int tid = threadIdx.x;
    const int lane = tid & 63;
    const int wave = tid >> 6;
    const float* p = logits + (size_t)row * VOCAB;

    // 8 floats/thread via two float4 loads (coalesced, 16B/lane)
    float4 a = ((const float4*)p)[tid];        // elems [4*tid, 4*tid+4)
    float4 b = ((const float4*)p)[tid + 256];  // elems [1024+4*tid, ...)

    float m = fmaxf(fmaxf(fmaxf(a.x, a.y), fmaxf(a.z, a.w)),
                    fmaxf(fmaxf(b.x, b.y), fmaxf(b.z, b.w)));

    __shared__ float red[4];
    float wm = waveRedMax(m);
    if (lane == 0) red[wave] = wm;
    __syncthreads();
    const float bm = fmaxf(fmaxf(red[0], red[1]), fmaxf(red[2], red[3]));
    __syncthreads();  // red reused below

    float s = expf(a.x - bm) + expf(a.y - bm) + expf(a.z - bm) + expf(a.w - bm)
            + expf(b.x - bm) + expf(b.y - bm) + expf(b.z - bm) + expf(b.w - bm);
    float ws_ = waveRedSum(s);
    if (lane == 0) red[wave] = ws_;
    __syncthreads();

    if (tid == 0) {
        const float bs = red[0] + red[1] + red[2] + red[3];
        const int t = tgt[row];
        float nll = 0.0f, valid = 0.0f;
        if (t != -100) {
            const float xt = p[t];  // L1/L2 hit (row just streamed)
            nll = -(xt - bm - logf(bs));
            valid = 1.0f;
        }
        nll_out[row] = nll;
        valid_out[row] = valid;
    }
}

// ---------------- chord CE: one wave (64 lanes) per row of 60 ----------------
__global__ __launch_bounds__(256) void ce_chord_kernel(
    const float* __restrict__ cl, const int* __restrict__ ct,
    float* __restrict__ nll_out, float* __restrict__ valid_out, int nrows) {
    const int lane = threadIdx.x & 63;
    const int row = blockIdx.x * 4 + (threadIdx.x >> 6);
    if (row >= nrows) return;  // no __syncthreads in this kernel -> safe
    const float* p = cl + (size_t)row * CHORDV;

    float x = (lane < CHORDV) ? p[lane] : -INFINITY;
    float m = waveRedMax(x);
    float e = (lane < CHORDV) ? expf(x - m) : 0.0f;
    float s = waveRedSum(e);

    if (lane == 0) {
        const int t = ct[row];
        float nll = 0.0f, valid = 0.0f;
        if (t != -1000000000) {  // ignore_index = -(10**9)
            nll = -(p[t] - m - logf(s));
            valid = 1.0f;
        }
        nll_out[row] = nll;
        valid_out[row] = valid;
    }
}

// ---------------- scale BCE-with-logits: elementwise, float4 ----------------
__device__ __forceinline__ float bce1(float x, float z) {
    return fmaxf(x, 0.0f) - x * z + log1pf(expf(-fabsf(x)));
}

__global__ __launch_bounds__(256) void bce_scale_kernel(
    const float* __restrict__ x, const float* __restrict__ z,
    float* __restrict__ partials, int n4) {
    const int i = blockIdx.x * 256 + threadIdx.x;
    const int lane = threadIdx.x & 63;
    const int wave = threadIdx.x >> 6;
    float s = 0.0f;
    if (i < n4) {
        float4 xv = ((const float4*)x)[i];
        float4 zv = ((const float4*)z)[i];
        s = bce1(xv.x, zv.x) + bce1(xv.y, zv.y) + bce1(xv.z, zv.z) + bce1(xv.w, zv.w);
    }
    __shared__ float red[4];
    float wsum = waveRedSum(s);
    if (lane == 0) red[wave] = wsum;
    __syncthreads();
    if (threadIdx.x == 0)
        partials[blockIdx.x] = red[0] + red[1] + red[2] + red[3];
}

// ---------------- finalize: reduce ws arrays, combine ----------------
__device__ __forceinline__ float blockSum256(float v, float* red) {
    const int lane = threadIdx.x & 63;
    const int wave = threadIdx.x >> 6;
    float w = waveRedSum(v);
    __syncthreads();  // guard red reuse across calls
    if (lane == 0) red[wave] = w;
    __syncthreads();
    return red[0] + red[1] + red[2] + red[3];
}

__global__ __launch_bounds__(256) void finalize_kernel(
    const float* __restrict__ ws, int BS, int S, int nScaleBlocks, int scaleN,
    float* __restrict__ out) {
    const int tid = threadIdx.x;
    float sm = 0.f, svm = 0.f, sc = 0.f, svc = 0.f, ss = 0.f;
    for (int i = tid; i < BS; i += 256) {
        sm  += ws[i];
        svm += ws[BS + i];
        sc  += ws[2 * BS + i];
        svc += ws[3 * BS + i];
    }
    for (int i = tid; i < nScaleBlocks; i += 256) ss += ws[4 * BS + i];

    __shared__ float red[4];
    sm  = blockSum256(sm,  red);
    svm = blockSum256(svm, red);
    sc  = blockSum256(sc,  red);
    svc = blockSum256(svc, red);
    ss  = blockSum256(ss,  red);

    if (tid == 0) {
        const float main_loss  = sm / fmaxf(svm, 1.0f);
        const float chord_loss = sc / fmaxf(svc, 1.0f);
        const float scale_loss = ss / (float)scaleN;
        // rep_loss: data-independent constant (see header comment)
        double wsum = (S >= 8) ? (28.0 + 8.0 * (double)(S - 8))
                               : ((double)S * (double)(S - 1) * 0.5);
        const float rep_loss = (float)(0.5 * wsum / ((double)S * (double)VOCAB));
        out[0] = main_loss + 0.05f * rep_loss + 0.2f * chord_loss + 0.1f * scale_loss;
    }
}

extern "C" void kernel_launch(void* const* d_in, const int* in_sizes, int n_in,
                              void* d_out, int out_size, void* d_ws, size_t ws_size,
                              hipStream_t stream) {
    const float* logits        = (const float*)d_in[0];  // [B,S,2048]
    const float* chord_logits  = (const float*)d_in[1];  // [B,S,60]
    const float* scale_logits  = (const float*)d_in[2];  // [B,S,12]
    const float* scale_targets = (const float*)d_in[3];  // [B,S,12]
    const int*   target_ids    = (const int*)d_in[4];    // [B,S]
    // d_in[5] = key_ids [B] — unused by the reference
    const int*   chord_targets = (const int*)d_in[6];    // [B,S]

    const int BS = in_sizes[4];       // B*S
    const int B  = in_sizes[5];
    const int S  = BS / B;
    const int scaleN = in_sizes[2];   // B*S*12 (divisible by 4)
    const int n4 = scaleN / 4;
    const int nScaleBlocks = (n4 + 255) / 256;

    float* ws = (float*)d_ws;
    // layout: [0,BS) main_nll | [BS,2BS) main_valid | [2BS,3BS) chord_nll
    //         [3BS,4BS) chord_valid | [4BS, 4BS+nScaleBlocks) scale partials
    // every slot read by finalize is written each call -> no memset needed.

    ce_main_kernel<<<BS, 256, 0, stream>>>(logits, target_ids, ws, ws + BS);
    ce_chord_kernel<<<(BS + 3) / 4, 256, 0, stream>>>(chord_logits, chord_targets,
                                                      ws + 2 * BS, ws + 3 * BS, BS);
    bce_scale_kernel<<<nScaleBlocks, 256, 0, stream>>>(scale_logits, scale_targets,
                                                       ws + 4 * BS, n4);
    finalize_kernel<<<1, 256, 0, stream>>>(ws, BS, S, nScaleBlocks, scaleN,
                                           (float*)d_out);
}

// Round 3
// 113.829 us; speedup vs baseline: 1.0330x; 1.0330x over previous
//
#include <hip/hip_runtime.h>
#include <math.h>

// total = main_ce + 0.05*rep + 0.2*chord_ce + 0.1*scale_bce
// rep_loss is data-independent: 0.5 * sum_pos min(pos,8) / (S*VOCAB)
// (one-hot rows sum to 1 since ids are always in [0,VOCAB)).

#define VOCAB 2048
#define CHORDV 60

// native vector type: required by __builtin_nontemporal_load (HIP float4 is a struct)
typedef float vf4 __attribute__((ext_vector_type(4)));

__device__ __forceinline__ float waveRedMax(float v) {
#pragma unroll
    for (int off = 32; off > 0; off >>= 1)
        v = fmaxf(v, __shfl_xor(v, off, 64));
    return v;
}

__device__ __forceinline__ float waveRedSum(float v) {
#pragma unroll
    for (int off = 32; off > 0; off >>= 1)
        v += __shfl_xor(v, off, 64);
    return v;
}

__device__ __forceinline__ float bce1(float x, float z) {
    // numerically stable BCE-with-logits; __expf/__logf -> v_exp_f32/v_log_f32
    return fmaxf(x, 0.0f) - x * z + __logf(1.0f + __expf(-fabsf(x)));
}

// ---------------- fused leaf kernel ----------------
// blocks [0, BS): main CE, one row of 2048 per block
// blocks [BS, BS+chordBlocks): chord CE, 4 rows of 60 per block (1/wave), pre-reduced
// blocks [BS+chordBlocks, ...): scale BCE, 1024 elems per block
__global__ __launch_bounds__(256) void fused_leaf_kernel(
    const float* __restrict__ logits, const int* __restrict__ tgt,
    const float* __restrict__ chordL, const int* __restrict__ chordT,
    const float* __restrict__ sx, const float* __restrict__ sz,
    float2* __restrict__ mainNV, float2* __restrict__ chordNV,
    float* __restrict__ scaleP, int BS, int chordBlocks, int n4) {
    const int bid = blockIdx.x;
    const int tid = threadIdx.x;
    const int lane = tid & 63;
    const int wave = tid >> 6;

    __shared__ float red[4];
    __shared__ float xt_sh;
    __shared__ float2 csh[4];

    if (bid < BS) {
        // ---- main CE row ----
        const int row = bid;
        const int t = tgt[row];  // issued first: latency overlaps the row stream
        const float* p = logits + (size_t)row * VOCAB;

        // 8 floats/thread, 16B/lane, read-once stream -> nontemporal
        vf4 a = __builtin_nontemporal_load(((const vf4*)p) + tid);
        vf4 b = __builtin_nontemporal_load(((const vf4*)p) + tid + 256);

        // target logit from the owning thread's registers (no global reload)
        const bool valid = (t >= 0) && (t < VOCAB);
        if (valid) {
            const int owner = t >> 2;          // vf4 index owning element t
            const int comp = t & 3;
            if (owner == tid) {
                xt_sh = a[comp];
            } else if (owner == tid + 256) {
                xt_sh = b[comp];
            }
        }

        float m = fmaxf(fmaxf(fmaxf(a[0], a[1]), fmaxf(a[2], a[3])),
                        fmaxf(fmaxf(b[0], b[1]), fmaxf(b[2], b[3])));
        float wm = waveRedMax(m);
        if (lane == 0) red[wave] = wm;
        __syncthreads();
        const float bm = fmaxf(fmaxf(red[0], red[1]), fmaxf(red[2], red[3]));
        __syncthreads();  // red reused

        float s = __expf(a[0] - bm) + __expf(a[1] - bm) + __expf(a[2] - bm) + __expf(a[3] - bm)
                + __expf(b[0] - bm) + __expf(b[1] - bm) + __expf(b[2] - bm) + __expf(b[3] - bm);
        float ws_ = waveRedSum(s);
        if (lane == 0) red[wave] = ws_;
        __syncthreads();

        if (tid == 0) {
            const float bs = red[0] + red[1] + red[2] + red[3];
            float2 nv = make_float2(0.0f, 0.0f);
            if (valid) {
                nv.x = -(xt_sh - bm - __logf(bs));
                nv.y = 1.0f;
            }
            mainNV[row] = nv;
        }
    } else if (bid < BS + chordBlocks) {
        // ---- chord CE: 4 rows, one per wave, pre-reduced to one float2 ----
        const int cb = bid - BS;
        const int row = cb * 4 + wave;
        float2 nv = make_float2(0.0f, 0.0f);
        if (row < BS) {
            const float* p = chordL + (size_t)row * CHORDV;
            const int t = chordT[row];
            float x = (lane < CHORDV) ? p[lane] : -INFINITY;
            float m = waveRedMax(x);
            float e = (lane < CHORDV) ? __expf(x - m) : 0.0f;
            float s = waveRedSum(e);
            if (t != -1000000000) {  // ignore_index = -(10**9), never hit here
                nv.x = -(p[t] - m - __logf(s));
                nv.y = 1.0f;
            }
        }
        if (lane == 0) csh[wave] = nv;
        __syncthreads();
        if (tid == 0) {
            chordNV[cb] = make_float2(csh[0].x + csh[1].x + csh[2].x + csh[3].x,
                                      csh[0].y + csh[1].y + csh[2].y + csh[3].y);
        }
    } else {
        // ---- scale BCE ----
        const int sb = bid - BS - chordBlocks;
        const int i = sb * 256 + tid;
        float s = 0.0f;
        if (i < n4) {
            float4 xv = ((const float4*)sx)[i];
            float4 zv = ((const float4*)sz)[i];
            s = bce1(xv.x, zv.x) + bce1(xv.y, zv.y) + bce1(xv.z, zv.z) + bce1(xv.w, zv.w);
        }
        float wsum = waveRedSum(s);
        if (lane == 0) red[wave] = wsum;
        __syncthreads();
        if (tid == 0) scaleP[sb] = red[0] + red[1] + red[2] + red[3];
    }
}

// ---------------- finalize: 1 block x 1024 threads ----------------
__device__ __forceinline__ float blockSum1024(float v, float* red16) {
    const int lane = threadIdx.x & 63;
    const int wave = threadIdx.x >> 6;
    float w = waveRedSum(v);
    __syncthreads();  // guard reuse across calls
    if (lane == 0) red16[wave] = w;
    __syncthreads();
    float r = 0.0f;
#pragma unroll
    for (int k = 0; k < 16; ++k) r += red16[k];  // LDS broadcast, conflict-free
    return r;
}

__global__ __launch_bounds__(1024) void finalize_kernel(
    const float2* __restrict__ mainNV, const float2* __restrict__ chordNV,
    const float* __restrict__ scaleP, int BS, int chordBlocks, int nScaleBlocks,
    int S, int scaleN, float* __restrict__ out) {
    const int tid = threadIdx.x;
    float sm = 0.f, svm = 0.f, sc = 0.f, svc = 0.f, ss = 0.f;

    const float4* m4 = (const float4*)mainNV;  // (nll,valid) pairs, float4 = 2 rows
    for (int i = tid; i < BS / 2; i += 1024) {
        float4 v = m4[i];
        sm += v.x + v.z;
        svm += v.y + v.w;
    }
    if ((BS & 1) && tid == 0) { float2 v = mainNV[BS - 1]; sm += v.x; svm += v.y; }

    const float4* c4 = (const float4*)chordNV;
    for (int i = tid; i < chordBlocks / 2; i += 1024) {
        float4 v = c4[i];
        sc += v.x + v.z;
        svc += v.y + v.w;
    }
    if ((chordBlocks & 1) && tid == 0) { float2 v = chordNV[chordBlocks - 1]; sc += v.x; svc += v.y; }

    for (int i = tid; i < nScaleBlocks; i += 1024) ss += scaleP[i];

    __shared__ float red16[16];
    sm  = blockSum1024(sm,  red16);
    svm = blockSum1024(svm, red16);
    sc  = blockSum1024(sc,  red16);
    svc = blockSum1024(svc, red16);
    ss  = blockSum1024(ss,  red16);

    if (tid == 0) {
        const float main_loss  = sm / fmaxf(svm, 1.0f);
        const float chord_loss = sc / fmaxf(svc, 1.0f);
        const float scale_loss = ss / (float)scaleN;
        // rep_loss: data-independent constant (header comment)
        double wsum = (S >= 8) ? (28.0 + 8.0 * (double)(S - 8))
                               : ((double)S * (double)(S - 1) * 0.5);
        const float rep_loss = (float)(0.5 * wsum / ((double)S * (double)VOCAB));
        out[0] = main_loss + 0.05f * rep_loss + 0.2f * chord_loss + 0.1f * scale_loss;
    }
}

extern "C" void kernel_launch(void* const* d_in, const int* in_sizes, int n_in,
                              void* d_out, int out_size, void* d_ws, size_t ws_size,
                              hipStream_t stream) {
    const float* logits        = (const float*)d_in[0];  // [B,S,2048]
    const float* chord_logits  = (const float*)d_in[1];  // [B,S,60]
    const float* scale_logits  = (const float*)d_in[2];  // [B,S,12]
    const float* scale_targets = (const float*)d_in[3];  // [B,S,12]
    const int*   target_ids    = (const int*)d_in[4];    // [B,S]
    // d_in[5] = key_ids [B] — unused by the reference
    const int*   chord_targets = (const int*)d_in[6];    // [B,S]

    const int BS = in_sizes[4];       // B*S = 8192
    const int B  = in_sizes[5];
    const int S  = BS / B;
    const int scaleN = in_sizes[2];   // B*S*12 (divisible by 4)
    const int n4 = scaleN / 4;
    const int nScaleBlocks = (n4 + 255) / 256;
    const int chordBlocks = (BS + 3) / 4;

    // ws layout (all written every call before being read — poison-safe):
    // [0, BS) float2 main (nll,valid) | [BS, BS+chordBlocks) float2 chord
    // then nScaleBlocks floats of scale partials
    float2* mainNV  = (float2*)d_ws;
    float2* chordNV = mainNV + BS;
    float*  scaleP  = (float*)(chordNV + chordBlocks);

    const int totalBlocks = BS + chordBlocks + nScaleBlocks;
    fused_leaf_kernel<<<totalBlocks, 256, 0, stream>>>(
        logits, target_ids, chord_logits, chord_targets,
        scale_logits, scale_targets, mainNV, chordNV, scaleP,
        BS, chordBlocks, n4);
    finalize_kernel<<<1, 1024, 0, stream>>>(mainNV, chordNV, scaleP,
                                            BS, chordBlocks, nScaleBlocks,
                                            S, scaleN, (float*)d_out);
}